// Round 1
// baseline (696.915 us; speedup 1.0000x reference)
//
#include <hip/hip_runtime.h>
#include <hip/hip_bf16.h>

#define T_STEPS 32
#define BATCH 256
#define EDIM 512
#define HDIM 512
#define G4 2048       // 4*H
#define VOCAB 3000
#define VPAD 3072

typedef short bf16x8 __attribute__((ext_vector_type(8)));
typedef float f32x4 __attribute__((ext_vector_type(4)));

__device__ __forceinline__ unsigned short f2b(float f){
  union { float f; unsigned int u; } x; x.f = f;
  unsigned int u = x.u;
  unsigned int r = (u + 0x7fffu + ((u >> 16) & 1u)) >> 16;
  return (unsigned short)r;
}
__device__ __forceinline__ float b2f(unsigned short h){
  union { unsigned int u; float f; } x; x.u = ((unsigned int)h) << 16;
  return x.f;
}
__device__ __forceinline__ float sigm(float x){ return 1.0f / (1.0f + expf(-x)); }

// ---------------- small prep kernels ----------------

__global__ void k_cvt(const float* __restrict__ in, unsigned short* __restrict__ out, int n){
  int i = blockIdx.x * blockDim.x + threadIdx.x;
  if (i < n) out[i] = f2b(in[i]);
}

__global__ void k_cvt_wout(const float* __restrict__ in, unsigned short* __restrict__ out){
  int i = blockIdx.x * blockDim.x + threadIdx.x; // over VPAD*1024
  if (i >= VPAD * 1024) return;
  int r = i >> 10, c = i & 1023;
  float v = (r < VOCAB) ? in[r * 1024 + c] : 0.0f;
  out[i] = f2b(v);
}

__global__ void k_build_xs(const float* __restrict__ img, const float* __restrict__ txt,
                           const float* __restrict__ emb, const int* __restrict__ ans,
                           unsigned short* __restrict__ xs){
  int i = blockIdx.x * blockDim.x + threadIdx.x; // over T*B*E
  if (i >= T_STEPS * BATCH * EDIM) return;
  int e = i & (EDIM - 1);
  int r = i >> 9;              // t*B + b
  int t = r >> 8, b = r & 255;
  float v;
  if (t == 0) v = (e < 256) ? img[b * 256 + e] : txt[b * 256 + (e - 256)];
  else { int tok = ans[b * T_STEPS + (t - 1)]; v = emb[(size_t)tok * EDIM + e]; }
  xs[i] = f2b(v);
}

__global__ void k_init_carry(const float* __restrict__ h0, const float* __restrict__ c0,
                             unsigned short* __restrict__ hx, float* __restrict__ cx){
  int i = blockIdx.x * blockDim.x + threadIdx.x;
  if (i < BATCH * HDIM){ hx[i] = f2b(h0[i]); cx[i] = c0[i]; }
}

// batch_sizes[t] = #lengths > t ; roff[t] = prefix sum (packed row offsets)
__global__ void k_lens(const int* __restrict__ lengths, int* __restrict__ bs, int* __restrict__ roff){
  __shared__ int s[T_STEPS];
  int t = threadIdx.x;
  if (t < T_STEPS){
    int c = 0;
    for (int i = 0; i < BATCH; i++) c += (lengths[i] > t) ? 1 : 0;
    s[t] = c; bs[t] = c;
  }
  __syncthreads();
  if (t == 0){
    int acc = 0;
    for (int u = 0; u < T_STEPS; u++){ roff[u] = acc; acc += s[u]; }
  }
}

// ---------------- GEMM 1: XW = xs @ W_ih^T + b_ih + b_hh  (fp32 out) ----------------
// C[8192,2048], A[8192,512] bf16, W[2048,512] bf16 (both K-contiguous)
__global__ __launch_bounds__(256) void k_gemm_xw(const unsigned short* __restrict__ A,
                                                 const unsigned short* __restrict__ W,
                                                 const float* __restrict__ bih,
                                                 const float* __restrict__ bhh,
                                                 float* __restrict__ C){
  const int K = EDIM, N = G4;
  int w = threadIdx.x >> 6, l = threadIdx.x & 63;
  int row0 = blockIdx.x * 128 + (w >> 1) * 64;
  int col0 = blockIdx.y * 128 + (w & 1) * 64;
  int la = l & 15, lk = (l >> 4) * 8;
  f32x4 acc[4][4] = {};
  const unsigned short* Ap = A + (size_t)(row0 + la) * K + lk;
  const unsigned short* Wp = W + (size_t)(col0 + la) * K + lk;
  for (int k0 = 0; k0 < K; k0 += 32){
    bf16x8 a[4], b[4];
#pragma unroll
    for (int i = 0; i < 4; i++) a[i] = *(const bf16x8*)(Ap + (size_t)i * 16 * K + k0);
#pragma unroll
    for (int i = 0; i < 4; i++) b[i] = *(const bf16x8*)(Wp + (size_t)i * 16 * K + k0);
#pragma unroll
    for (int mi = 0; mi < 4; mi++)
#pragma unroll
      for (int ni = 0; ni < 4; ni++)
        acc[mi][ni] = __builtin_amdgcn_mfma_f32_16x16x32_bf16(a[mi], b[ni], acc[mi][ni], 0, 0, 0);
  }
  int r4 = (l >> 4) * 4;
#pragma unroll
  for (int ni = 0; ni < 4; ni++){
    int col = col0 + ni * 16 + la;
    float bias = bih[col] + bhh[col];
#pragma unroll
    for (int mi = 0; mi < 4; mi++)
#pragma unroll
      for (int j = 0; j < 4; j++){
        int row = row0 + mi * 16 + r4 + j;
        C[(size_t)row * N + col] = acc[mi][ni][j] + bias;
      }
  }
}

// ---------------- fused recurrent step ----------------
// grid (16,8): block = rows [16] x h-cols [64]; wave w computes gate w for that tile.
// gates = XW[t] + hin @ W_hh^T ; then LSTM cell + skip residual, carry ping-pong.
__global__ __launch_bounds__(256) void k_lstm_step(const float* __restrict__ XWt,
                                                   const unsigned short* __restrict__ Whh,
                                                   const unsigned short* __restrict__ hin,
                                                   unsigned short* __restrict__ hout,
                                                   float* __restrict__ cx,
                                                   unsigned short* __restrict__ hs_t,
                                                   unsigned short* __restrict__ cs_t,
                                                   const unsigned short* __restrict__ hs_m2,
                                                   const unsigned short* __restrict__ cs_m2,
                                                   int do_res){
  __shared__ float gbuf[4][16][65];
  int w = threadIdx.x >> 6, l = threadIdx.x & 63;
  int row0 = blockIdx.x * 16;
  int h0 = blockIdx.y * 64;
  int la = l & 15, lk = (l >> 4) * 8;
  f32x4 acc[4] = {};
  const unsigned short* Ap = hin + (size_t)(row0 + la) * HDIM + lk;
  const unsigned short* Wp = Whh + (size_t)(w * HDIM + h0 + la) * HDIM + lk;
  for (int k0 = 0; k0 < HDIM; k0 += 32){
    bf16x8 a = *(const bf16x8*)(Ap + k0);
    bf16x8 b[4];
#pragma unroll
    for (int i = 0; i < 4; i++) b[i] = *(const bf16x8*)(Wp + (size_t)i * 16 * HDIM + k0);
#pragma unroll
    for (int ni = 0; ni < 4; ni++)
      acc[ni] = __builtin_amdgcn_mfma_f32_16x16x32_bf16(a, b[ni], acc[ni], 0, 0, 0);
  }
  int r4 = (l >> 4) * 4;
#pragma unroll
  for (int ni = 0; ni < 4; ni++)
#pragma unroll
    for (int j = 0; j < 4; j++){
      int r = r4 + j, c = ni * 16 + la;
      gbuf[w][r][c] = acc[ni][j] + XWt[(size_t)(row0 + r) * G4 + w * HDIM + h0 + c];
    }
  __syncthreads();
  for (int idx = threadIdx.x; idx < 16 * 64; idx += 256){
    int r = idx >> 6, c = idx & 63;
    int b = row0 + r, h = h0 + c;
    size_t p = (size_t)b * HDIM + h;
    float gi = gbuf[0][r][c], gf = gbuf[1][r][c], gg = gbuf[2][r][c], go = gbuf[3][r][c];
    float cprev = cx[p];
    float cy = sigm(gf) * cprev + sigm(gi) * tanhf(gg);
    float hy = sigm(go) * tanhf(cy);
    hs_t[p] = f2b(hy);
    cs_t[p] = f2b(cy);
    float hn = hy, cn = cy;
    if (do_res){ hn += b2f(hs_m2[p]); cn += b2f(cs_m2[p]); }
    hout[p] = f2b(hn);
    cx[p] = cn;
  }
}

// ---------------- GEMM 2: packed output projection ----------------
// rows r = t*256+b over all 8192; A row = [hs[r,:512] | cs[r,:512]]; write only b < bs[t]
__global__ __launch_bounds__(256) void k_gemm_out(const unsigned short* __restrict__ hsf,
                                                  const unsigned short* __restrict__ csf,
                                                  const unsigned short* __restrict__ Wo,
                                                  const float* __restrict__ bout,
                                                  const int* __restrict__ bs,
                                                  const int* __restrict__ roff,
                                                  float* __restrict__ out){
  int w = threadIdx.x >> 6, l = threadIdx.x & 63;
  int row0 = blockIdx.x * 128 + (w >> 1) * 64;
  int col0 = blockIdx.y * 128 + (w & 1) * 64;
  int la = l & 15, lk = (l >> 4) * 8;
  f32x4 acc[4][4] = {};
  const unsigned short* Wp = Wo + (size_t)(col0 + la) * 1024 + lk;
  for (int k0 = 0; k0 < 1024; k0 += 32){
    const unsigned short* Abase = (k0 < 512)
        ? (hsf + (size_t)(row0 + la) * 512 + lk + k0)
        : (csf + (size_t)(row0 + la) * 512 + lk + (k0 - 512));
    bf16x8 a[4], b[4];
#pragma unroll
    for (int i = 0; i < 4; i++) a[i] = *(const bf16x8*)(Abase + (size_t)i * 16 * 512);
#pragma unroll
    for (int i = 0; i < 4; i++) b[i] = *(const bf16x8*)(Wp + (size_t)i * 16 * 1024 + k0);
#pragma unroll
    for (int mi = 0; mi < 4; mi++)
#pragma unroll
      for (int ni = 0; ni < 4; ni++)
        acc[mi][ni] = __builtin_amdgcn_mfma_f32_16x16x32_bf16(a[mi], b[ni], acc[mi][ni], 0, 0, 0);
  }
  int r4 = (l >> 4) * 4;
#pragma unroll
  for (int ni = 0; ni < 4; ni++){
    int col = col0 + ni * 16 + la;
    if (col >= VOCAB) continue;
    float bias = bout[col];
#pragma unroll
    for (int mi = 0; mi < 4; mi++)
#pragma unroll
      for (int j = 0; j < 4; j++){
        int row = row0 + mi * 16 + r4 + j;
        int t = row >> 8, b = row & 255;
        if (b < bs[t]) out[(size_t)(roff[t] + b) * VOCAB + col] = acc[mi][ni][j] + bias;
      }
  }
}

extern "C" void kernel_launch(void* const* d_in, const int* in_sizes, int n_in,
                              void* d_out, int out_size, void* d_ws, size_t ws_size,
                              hipStream_t stream){
  const float* img   = (const float*)d_in[0];
  const float* txt   = (const float*)d_in[1];
  const float* h0    = (const float*)d_in[2];
  const float* c0    = (const float*)d_in[3];
  const float* emb   = (const float*)d_in[4];
  const float* W_ih  = (const float*)d_in[5];
  const float* W_hh  = (const float*)d_in[6];
  const float* b_ih  = (const float*)d_in[7];
  const float* b_hh  = (const float*)d_in[8];
  const float* W_out = (const float*)d_in[9];
  const float* b_out = (const float*)d_in[10];
  const int* answer  = (const int*)d_in[11];
  const int* lengths = (const int*)d_in[12];
  float* out = (float*)d_out;

  char* ws = (char*)d_ws;
  size_t off = 0;
  auto alloc = [&](size_t bytes) -> void* {
    void* p = ws + off; off += (bytes + 255) & ~(size_t)255; return p;
  };
  unsigned short* Wih_b = (unsigned short*)alloc((size_t)G4 * EDIM * 2);
  unsigned short* Whh_b = (unsigned short*)alloc((size_t)G4 * HDIM * 2);
  unsigned short* Wo_b  = (unsigned short*)alloc((size_t)VPAD * 1024 * 2);
  unsigned short* xs    = (unsigned short*)alloc((size_t)T_STEPS * BATCH * EDIM * 2);
  float* XW             = (float*)alloc((size_t)T_STEPS * BATCH * G4 * 4);
  unsigned short* hs    = (unsigned short*)alloc((size_t)T_STEPS * BATCH * HDIM * 2);
  unsigned short* cs    = (unsigned short*)alloc((size_t)T_STEPS * BATCH * HDIM * 2);
  unsigned short* hxA   = (unsigned short*)alloc((size_t)BATCH * HDIM * 2);
  unsigned short* hxB   = (unsigned short*)alloc((size_t)BATCH * HDIM * 2);
  float* cx             = (float*)alloc((size_t)BATCH * HDIM * 4);
  int* bsz  = (int*)alloc(T_STEPS * 4);
  int* roff = (int*)alloc(T_STEPS * 4);

  k_cvt<<<(G4 * EDIM + 255) / 256, 256, 0, stream>>>(W_ih, Wih_b, G4 * EDIM);
  k_cvt<<<(G4 * HDIM + 255) / 256, 256, 0, stream>>>(W_hh, Whh_b, G4 * HDIM);
  k_cvt_wout<<<(VPAD * 1024 + 255) / 256, 256, 0, stream>>>(W_out, Wo_b);
  k_build_xs<<<(T_STEPS * BATCH * EDIM + 255) / 256, 256, 0, stream>>>(img, txt, emb, answer, xs);
  k_init_carry<<<(BATCH * HDIM + 255) / 256, 256, 0, stream>>>(h0, c0, hxA, cx);
  k_lens<<<1, 64, 0, stream>>>(lengths, bsz, roff);

  k_gemm_xw<<<dim3(T_STEPS * BATCH / 128, G4 / 128), 256, 0, stream>>>(xs, Wih_b, b_ih, b_hh, XW);

  unsigned short* hbuf[2] = { hxA, hxB };
  for (int t = 0; t < T_STEPS; t++){
    int do_res = (t >= 2 && (t % 3) == 0) ? 1 : 0;
    int tm2 = (t >= 2) ? (t - 2) : 0;
    k_lstm_step<<<dim3(BATCH / 16, HDIM / 64), 256, 0, stream>>>(
        XW + (size_t)t * BATCH * G4, Whh_b, hbuf[t & 1], hbuf[(t + 1) & 1], cx,
        hs + (size_t)t * BATCH * HDIM, cs + (size_t)t * BATCH * HDIM,
        hs + (size_t)tm2 * BATCH * HDIM, cs + (size_t)tm2 * BATCH * HDIM, do_res);
  }

  k_gemm_out<<<dim3(T_STEPS * BATCH / 128, VPAD / 128), 256, 0, stream>>>(hs, cs, Wo_b, b_out, bsz, roff, out);
}

// Round 2
// 556.013 us; speedup vs baseline: 1.2534x; 1.2534x over previous
//
#include <hip/hip_runtime.h>
#include <hip/hip_bf16.h>

#define T_STEPS 32
#define BATCH 256
#define EDIM 512
#define HDIM 512
#define G4 2048       // 4*H
#define VOCAB 3000
#define VPAD 3072

typedef short bf16x8 __attribute__((ext_vector_type(8)));
typedef float f32x4 __attribute__((ext_vector_type(4)));

__device__ __forceinline__ unsigned short f2b(float f){
  union { float f; unsigned int u; } x; x.f = f;
  unsigned int u = x.u;
  unsigned int r = (u + 0x7fffu + ((u >> 16) & 1u)) >> 16;
  return (unsigned short)r;
}
__device__ __forceinline__ float b2f(unsigned short h){
  union { unsigned int u; float f; } x; x.u = ((unsigned int)h) << 16;
  return x.f;
}
__device__ __forceinline__ float sigm(float x){ return 1.0f / (1.0f + expf(-x)); }

__device__ __forceinline__ void gload_lds16(const unsigned short* g, unsigned short* l){
  __builtin_amdgcn_global_load_lds(
      (const __attribute__((address_space(1))) unsigned int*)g,
      (__attribute__((address_space(3))) unsigned int*)l, 16, 0, 0);
}

// ---------------- small prep kernels ----------------

__global__ void k_cvt(const float* __restrict__ in, unsigned short* __restrict__ out, int n){
  int i = blockIdx.x * blockDim.x + threadIdx.x;
  if (i < n) out[i] = f2b(in[i]);
}

__global__ void k_cvt_wout(const float* __restrict__ in, unsigned short* __restrict__ out){
  int i = blockIdx.x * blockDim.x + threadIdx.x; // over VPAD*1024
  if (i >= VPAD * 1024) return;
  int r = i >> 10, c = i & 1023;
  float v = (r < VOCAB) ? in[r * 1024 + c] : 0.0f;
  out[i] = f2b(v);
}

__global__ void k_build_xs(const float* __restrict__ img, const float* __restrict__ txt,
                           const float* __restrict__ emb, const int* __restrict__ ans,
                           unsigned short* __restrict__ xs){
  int i = blockIdx.x * blockDim.x + threadIdx.x; // over T*B*E
  if (i >= T_STEPS * BATCH * EDIM) return;
  int e = i & (EDIM - 1);
  int r = i >> 9;              // t*B + b
  int t = r >> 8, b = r & 255;
  float v;
  if (t == 0) v = (e < 256) ? img[b * 256 + e] : txt[b * 256 + (e - 256)];
  else { int tok = ans[b * T_STEPS + (t - 1)]; v = emb[(size_t)tok * EDIM + e]; }
  xs[i] = f2b(v);
}

__global__ void k_init_carry(const float* __restrict__ h0, const float* __restrict__ c0,
                             unsigned short* __restrict__ hx, float* __restrict__ cx){
  int i = blockIdx.x * blockDim.x + threadIdx.x;
  if (i < BATCH * HDIM){ hx[i] = f2b(h0[i]); cx[i] = c0[i]; }
}

// batch_sizes, packed row offsets, total rows, dest->src row map
__global__ void k_lens(const int* __restrict__ lengths, int* __restrict__ bs,
                       int* __restrict__ roff, int* __restrict__ meta,
                       int* __restrict__ rmap){
  __shared__ int s[T_STEPS];
  __shared__ int sroff[T_STEPS + 1];
  int t = threadIdx.x; // 64 threads
  if (t < T_STEPS){
    int c = 0;
    for (int i = 0; i < BATCH; i++) c += (lengths[i] > t) ? 1 : 0;
    s[t] = c; bs[t] = c;
  }
  __syncthreads();
  if (t == 0){
    int acc = 0;
    for (int u = 0; u < T_STEPS; u++){ sroff[u] = acc; roff[u] = acc; acc += s[u]; }
    sroff[T_STEPS] = acc;
    meta[0] = acc;
  }
  __syncthreads();
  int ntot = sroff[T_STEPS];
  for (int r = t; r < T_STEPS * BATCH; r += 64){
    int tt = r >> 8, b = r & 255;
    if (b < s[tt]) rmap[sroff[tt] + b] = r;
  }
  for (int r = ntot + t; r < T_STEPS * BATCH; r += 64) rmap[r] = -1;
}

// gather hs||cs rows into packed dense A [8192][1024], zero tail rows
__global__ void k_pack(const unsigned short* __restrict__ hs, const unsigned short* __restrict__ cs,
                       const int* __restrict__ rmap, unsigned short* __restrict__ Ap){
  int i = blockIdx.x * 256 + threadIdx.x;   // over 8192*128 (8 elems/thread)
  int r = i >> 7, c = (i & 127) * 8;
  int src = rmap[r];
  bf16x8 v = {};
  if (src >= 0){
    v = (c < 512) ? *(const bf16x8*)(hs + (size_t)src * 512 + c)
                  : *(const bf16x8*)(cs + (size_t)src * 512 + (c - 512));
  }
  *(bf16x8*)(Ap + (size_t)r * 1024 + c) = v;
}

// ---------------- staged 128x128 GEMM core (m97 structure) ----------------
// A [*, K], B [*, K] both bf16 K-contiguous. BK=32, single LDS buffer, 2 barriers/step.
template<int K>
__device__ __forceinline__ void gemm_tile(const unsigned short* __restrict__ A,
                                          const unsigned short* __restrict__ B,
                                          int row0, int col0,
                                          unsigned short* As, unsigned short* Bs,
                                          f32x4 acc[4][4]){
  int tid = threadIdx.x;
  int w = tid >> 6, l = tid & 63;
  int la = l & 15, lk = (l >> 4) * 8;
  // staging: lane l of wave w covers LDS row = i*64 + w*16 + (l>>2), col elem (l&3)*8
  int srow = w * 16 + (l >> 2);
  int scol = (l & 3) * 8;
  const unsigned short* gA0 = A + (size_t)(row0 + srow) * K + scol;
  const unsigned short* gA1 = A + (size_t)(row0 + 64 + srow) * K + scol;
  const unsigned short* gB0 = B + (size_t)(col0 + srow) * K + scol;
  const unsigned short* gB1 = B + (size_t)(col0 + 64 + srow) * K + scol;
  unsigned short* lA0 = As + w * 512;        // wave-uniform LDS base, +lane*16 by HW
  unsigned short* lA1 = As + 2048 + w * 512;
  unsigned short* lB0 = Bs + w * 512;
  unsigned short* lB1 = Bs + 2048 + w * 512;
  int wr = (w >> 1) * 64, wc = (w & 1) * 64;
  for (int k0 = 0; k0 < K; k0 += 32){
    gload_lds16(gA0 + k0, lA0);
    gload_lds16(gA1 + k0, lA1);
    gload_lds16(gB0 + k0, lB0);
    gload_lds16(gB1 + k0, lB1);
    __syncthreads();   // compiler emits vmcnt(0) drain before barrier
    bf16x8 a[4], b[4];
#pragma unroll
    for (int i = 0; i < 4; i++) a[i] = *(const bf16x8*)(As + (wr + i * 16 + la) * 32 + lk);
#pragma unroll
    for (int i = 0; i < 4; i++) b[i] = *(const bf16x8*)(Bs + (wc + i * 16 + la) * 32 + lk);
#pragma unroll
    for (int mi = 0; mi < 4; mi++)
#pragma unroll
      for (int ni = 0; ni < 4; ni++)
        acc[mi][ni] = __builtin_amdgcn_mfma_f32_16x16x32_bf16(a[mi], b[ni], acc[mi][ni], 0, 0, 0);
    __syncthreads();
  }
}

// ---------------- GEMM 1: XW = xs @ W_ih^T + b_ih + b_hh  (fp32 out) ----------------
__global__ __launch_bounds__(256) void k_gemm_xw(const unsigned short* __restrict__ A,
                                                 const unsigned short* __restrict__ W,
                                                 const float* __restrict__ bih,
                                                 const float* __restrict__ bhh,
                                                 float* __restrict__ C){
  __shared__ unsigned short As[128 * 32], Bs[128 * 32];
  int row0 = blockIdx.x * 128, col0 = blockIdx.y * 128;
  f32x4 acc[4][4] = {};
  gemm_tile<EDIM>(A, W, row0, col0, As, Bs, acc);
  int tid = threadIdx.x, w = tid >> 6, l = tid & 63;
  int la = l & 15, r4 = (l >> 4) * 4;
  int wr = (w >> 1) * 64, wc = (w & 1) * 64;
#pragma unroll
  for (int ni = 0; ni < 4; ni++){
    int col = col0 + wc + ni * 16 + la;
    float bias = bih[col] + bhh[col];
#pragma unroll
    for (int mi = 0; mi < 4; mi++)
#pragma unroll
      for (int j = 0; j < 4; j++){
        int row = row0 + wr + mi * 16 + r4 + j;
        C[(size_t)row * G4 + col] = acc[mi][ni][j] + bias;
      }
  }
}

// ---------------- fused recurrent step (unchanged) ----------------
__global__ __launch_bounds__(256) void k_lstm_step(const float* __restrict__ XWt,
                                                   const unsigned short* __restrict__ Whh,
                                                   const unsigned short* __restrict__ hin,
                                                   unsigned short* __restrict__ hout,
                                                   float* __restrict__ cx,
                                                   unsigned short* __restrict__ hs_t,
                                                   unsigned short* __restrict__ cs_t,
                                                   const unsigned short* __restrict__ hs_m2,
                                                   const unsigned short* __restrict__ cs_m2,
                                                   int do_res){
  __shared__ float gbuf[4][16][65];
  int w = threadIdx.x >> 6, l = threadIdx.x & 63;
  int row0 = blockIdx.x * 16;
  int h0 = blockIdx.y * 64;
  int la = l & 15, lk = (l >> 4) * 8;
  f32x4 acc[4] = {};
  const unsigned short* Ap = hin + (size_t)(row0 + la) * HDIM + lk;
  const unsigned short* Wp = Whh + (size_t)(w * HDIM + h0 + la) * HDIM + lk;
  for (int k0 = 0; k0 < HDIM; k0 += 32){
    bf16x8 a = *(const bf16x8*)(Ap + k0);
    bf16x8 b[4];
#pragma unroll
    for (int i = 0; i < 4; i++) b[i] = *(const bf16x8*)(Wp + (size_t)i * 16 * HDIM + k0);
#pragma unroll
    for (int ni = 0; ni < 4; ni++)
      acc[ni] = __builtin_amdgcn_mfma_f32_16x16x32_bf16(a, b[ni], acc[ni], 0, 0, 0);
  }
  int r4 = (l >> 4) * 4;
#pragma unroll
  for (int ni = 0; ni < 4; ni++)
#pragma unroll
    for (int j = 0; j < 4; j++){
      int r = r4 + j, c = ni * 16 + la;
      gbuf[w][r][c] = acc[ni][j] + XWt[(size_t)(row0 + r) * G4 + w * HDIM + h0 + c];
    }
  __syncthreads();
  for (int idx = threadIdx.x; idx < 16 * 64; idx += 256){
    int r = idx >> 6, c = idx & 63;
    int b = row0 + r, h = h0 + c;
    size_t p = (size_t)b * HDIM + h;
    float gi = gbuf[0][r][c], gf = gbuf[1][r][c], gg = gbuf[2][r][c], go = gbuf[3][r][c];
    float cprev = cx[p];
    float cy = sigm(gf) * cprev + sigm(gi) * tanhf(gg);
    float hy = sigm(go) * tanhf(cy);
    hs_t[p] = f2b(hy);
    cs_t[p] = f2b(cy);
    float hn = hy, cn = cy;
    if (do_res){ hn += b2f(hs_m2[p]); cn += b2f(cs_m2[p]); }
    hout[p] = f2b(hn);
    cx[p] = cn;
  }
}

// ---------------- GEMM 2: packed output projection (dense rows) ----------------
__global__ __launch_bounds__(256) void k_gemm_out(const unsigned short* __restrict__ Ap,
                                                  const unsigned short* __restrict__ Wo,
                                                  const float* __restrict__ bout,
                                                  const int* __restrict__ meta,
                                                  float* __restrict__ out){
  int ntot = meta[0];
  int row0 = blockIdx.x * 128, col0 = blockIdx.y * 128;
  if (row0 >= ntot) return;
  __shared__ unsigned short As[128 * 32], Bs[128 * 32];
  f32x4 acc[4][4] = {};
  gemm_tile<1024>(Ap, Wo, row0, col0, As, Bs, acc);
  int tid = threadIdx.x, w = tid >> 6, l = tid & 63;
  int la = l & 15, r4 = (l >> 4) * 4;
  int wr = (w >> 1) * 64, wc = (w & 1) * 64;
#pragma unroll
  for (int ni = 0; ni < 4; ni++){
    int col = col0 + wc + ni * 16 + la;
    if (col >= VOCAB) continue;
    float bias = bout[col];
#pragma unroll
    for (int mi = 0; mi < 4; mi++)
#pragma unroll
      for (int j = 0; j < 4; j++){
        int row = row0 + wr + mi * 16 + r4 + j;
        if (row < ntot) out[(size_t)row * VOCAB + col] = acc[mi][ni][j] + bias;
      }
  }
}

extern "C" void kernel_launch(void* const* d_in, const int* in_sizes, int n_in,
                              void* d_out, int out_size, void* d_ws, size_t ws_size,
                              hipStream_t stream){
  const float* img   = (const float*)d_in[0];
  const float* txt   = (const float*)d_in[1];
  const float* h0    = (const float*)d_in[2];
  const float* c0    = (const float*)d_in[3];
  const float* emb   = (const float*)d_in[4];
  const float* W_ih  = (const float*)d_in[5];
  const float* W_hh  = (const float*)d_in[6];
  const float* b_ih  = (const float*)d_in[7];
  const float* b_hh  = (const float*)d_in[8];
  const float* W_out = (const float*)d_in[9];
  const float* b_out = (const float*)d_in[10];
  const int* answer  = (const int*)d_in[11];
  const int* lengths = (const int*)d_in[12];
  float* out = (float*)d_out;

  char* ws = (char*)d_ws;
  size_t off = 0;
  auto alloc = [&](size_t bytes) -> void* {
    void* p = ws + off; off += (bytes + 255) & ~(size_t)255; return p;
  };
  unsigned short* Wih_b = (unsigned short*)alloc((size_t)G4 * EDIM * 2);
  unsigned short* Whh_b = (unsigned short*)alloc((size_t)G4 * HDIM * 2);
  unsigned short* Wo_b  = (unsigned short*)alloc((size_t)VPAD * 1024 * 2);
  unsigned short* xs    = (unsigned short*)alloc((size_t)T_STEPS * BATCH * EDIM * 2);
  float* XW             = (float*)alloc((size_t)T_STEPS * BATCH * G4 * 4);
  unsigned short* hs    = (unsigned short*)alloc((size_t)T_STEPS * BATCH * HDIM * 2);
  unsigned short* cs    = (unsigned short*)alloc((size_t)T_STEPS * BATCH * HDIM * 2);
  unsigned short* hxA   = (unsigned short*)alloc((size_t)BATCH * HDIM * 2);
  unsigned short* hxB   = (unsigned short*)alloc((size_t)BATCH * HDIM * 2);
  float* cx             = (float*)alloc((size_t)BATCH * HDIM * 4);
  int* bsz  = (int*)alloc(T_STEPS * 4);
  int* roff = (int*)alloc(T_STEPS * 4);
  int* meta = (int*)alloc(256);
  int* rmap = (int*)alloc(T_STEPS * BATCH * 4);
  // Apack aliases XW: XW is dead after the last lstm step, k_pack runs after it.
  unsigned short* Apack = (unsigned short*)XW; // 8192 x 1024 bf16 = 16 MB (< 67 MB)

  k_cvt<<<(G4 * EDIM + 255) / 256, 256, 0, stream>>>(W_ih, Wih_b, G4 * EDIM);
  k_cvt<<<(G4 * HDIM + 255) / 256, 256, 0, stream>>>(W_hh, Whh_b, G4 * HDIM);
  k_cvt_wout<<<(VPAD * 1024 + 255) / 256, 256, 0, stream>>>(W_out, Wo_b);
  k_build_xs<<<(T_STEPS * BATCH * EDIM + 255) / 256, 256, 0, stream>>>(img, txt, emb, answer, xs);
  k_init_carry<<<(BATCH * HDIM + 255) / 256, 256, 0, stream>>>(h0, c0, hxA, cx);
  k_lens<<<1, 64, 0, stream>>>(lengths, bsz, roff, meta, rmap);

  k_gemm_xw<<<dim3(T_STEPS * BATCH / 128, G4 / 128), 256, 0, stream>>>(xs, Wih_b, b_ih, b_hh, XW);

  unsigned short* hbuf[2] = { hxA, hxB };
  for (int t = 0; t < T_STEPS; t++){
    int do_res = (t >= 2 && (t % 3) == 0) ? 1 : 0;
    int tm2 = (t >= 2) ? (t - 2) : 0;
    k_lstm_step<<<dim3(BATCH / 16, HDIM / 64), 256, 0, stream>>>(
        XW + (size_t)t * BATCH * G4, Whh_b, hbuf[t & 1], hbuf[(t + 1) & 1], cx,
        hs + (size_t)t * BATCH * HDIM, cs + (size_t)t * BATCH * HDIM,
        hs + (size_t)tm2 * BATCH * HDIM, cs + (size_t)tm2 * BATCH * HDIM, do_res);
  }

  k_pack<<<T_STEPS * BATCH * 128 / 256, 256, 0, stream>>>(hs, cs, rmap, Apack);
  k_gemm_out<<<dim3(T_STEPS * BATCH / 128, VPAD / 128), 256, 0, stream>>>(Apack, Wo_b, b_out, meta, out);
}